// Round 1
// baseline (1450.476 us; speedup 1.0000x reference)
//
#include <hip/hip_runtime.h>
#include <cstdint>
#include <cstddef>

// ---------- types ----------
typedef _Float16 half2v __attribute__((ext_vector_type(2)));
typedef _Float16 half4v __attribute__((ext_vector_type(4)));
typedef _Float16 half8v __attribute__((ext_vector_type(8)));
typedef float f32x4 __attribute__((ext_vector_type(4)));
typedef unsigned int uint2v __attribute__((ext_vector_type(2)));

#if __has_builtin(__builtin_amdgcn_fdot2)
#define FDOT2(a, b, c) __builtin_amdgcn_fdot2((a), (b), (c), false)
#else
static __device__ __forceinline__ float fdot2_fb(half2v a, half2v b, float c) {
    return c + (float)a[0] * (float)b[0] + (float)a[1] * (float)b[1];
}
#define FDOT2(a, b, c) fdot2_fb((a), (b), (c))
#endif

__device__ __forceinline__ float sigm(float x) { return 1.0f / (1.0f + __expf(-x)); }
__device__ __forceinline__ float tanh_(float x) { return 1.0f - 2.0f / (__expf(2.0f * x) + 1.0f); }

// xor-16 / xor-32 all-reduce on the VALU pipe (no ds_bpermute LDS traffic).
// Self-swap trick: permlaneN_swap(x, x) returns {a, b} where at every lane one
// of {a, b} is own x and the other is partner's x (whatever the swap direction
// convention is) -> a + b == x + partner_x at every lane.
static __device__ __forceinline__ float xred16(float x) {
#if __has_builtin(__builtin_amdgcn_permlane16_swap)
    uint2v r = __builtin_amdgcn_permlane16_swap(__float_as_uint(x), __float_as_uint(x), false, false);
    return __uint_as_float(r[0]) + __uint_as_float(r[1]);
#else
    return x + __shfl_xor(x, 16, 64);
#endif
}
static __device__ __forceinline__ float xred32(float x) {
#if __has_builtin(__builtin_amdgcn_permlane32_swap)
    uint2v r = __builtin_amdgcn_permlane32_swap(__float_as_uint(x), __float_as_uint(x), false, false);
    return __uint_as_float(r[0]) + __uint_as_float(r[1]);
#else
    return x + __shfl_xor(x, 32, 64);
#endif
}

// Problem constants
#define BB 128
#define TT 512
#define II 300
#define HH 256
#define GG 1024  // 4*H

// ============================================================================
// Kernel 1: xp GEMM.  XP[m][n] = sum_k X[m][k]*W[n][k] + bias[n]
// M = B*T = 65536, K = 300 (padded to 320), N = 1024. 128x128 tile / 256 thr.
// ============================================================================
__global__ __launch_bounds__(256, 3) void gemm_xp(
    const float* __restrict__ X, const float* __restrict__ W,
    const float* __restrict__ bias, _Float16* __restrict__ XP)
{
    __shared__ _Float16 As[128 * 32];
    __shared__ _Float16 Bs[128 * 32];

    const int t = threadIdx.x;
    const int m0 = blockIdx.y * 128;
    const int n0 = blockIdx.x * 128;
    const int kpos = t & 7;
    const int rbase = t >> 3;
    const int lane = t & 63;
    const int wv = t >> 6;
    const int mq = (wv >> 1) * 4;
    const int nq = (wv & 1) * 4;

    f32x4 acc[4][4];
#pragma unroll
    for (int i = 0; i < 4; ++i)
#pragma unroll
        for (int j = 0; j < 4; ++j) acc[i][j] = f32x4{0.f, 0.f, 0.f, 0.f};

    for (int kc = 0; kc < 320; kc += 32) {
        __syncthreads();
        const int k0 = kc + kpos * 4;
#pragma unroll
        for (int rr = 0; rr < 4; ++rr) {
            const int row = rbase + rr * 32;
            float4 va = {0.f, 0.f, 0.f, 0.f}, vb = {0.f, 0.f, 0.f, 0.f};
            if (k0 < 300) {
                va = *(const float4*)(X + (size_t)(m0 + row) * II + k0);
                vb = *(const float4*)(W + (size_t)(n0 + row) * II + k0);
            }
            const int idx = (row >> 4) * 512 + (kpos >> 1) * 128 + (row & 15) * 8 + (kpos & 1) * 4;
            half4v ha = {(_Float16)va.x, (_Float16)va.y, (_Float16)va.z, (_Float16)va.w};
            half4v hb = {(_Float16)vb.x, (_Float16)vb.y, (_Float16)vb.z, (_Float16)vb.w};
            *(half4v*)(&As[idx]) = ha;
            *(half4v*)(&Bs[idx]) = hb;
        }
        __syncthreads();

        half8v af[4], bf[4];
#pragma unroll
        for (int i = 0; i < 4; ++i) {
            af[i] = *(const half8v*)(&As[(mq + i) * 512 + (lane >> 4) * 128 + (lane & 15) * 8]);
            bf[i] = *(const half8v*)(&Bs[(nq + i) * 512 + (lane >> 4) * 128 + (lane & 15) * 8]);
        }
#pragma unroll
        for (int i = 0; i < 4; ++i)
#pragma unroll
            for (int j = 0; j < 4; ++j)
                acc[i][j] = __builtin_amdgcn_mfma_f32_16x16x32_f16(af[i], bf[j], acc[i][j], 0, 0, 0);
    }

#pragma unroll
    for (int j = 0; j < 4; ++j) {
        const int n = n0 + (nq + j) * 16 + (lane & 15);
        const float bv = bias[n];
#pragma unroll
        for (int i = 0; i < 4; ++i) {
#pragma unroll
            for (int r = 0; r < 4; ++r) {
                const int m = m0 + (mq + i) * 16 + (lane >> 4) * 4 + r;
                XP[(size_t)m * GG + n] = (_Float16)(acc[i][j][r] + bv);
            }
        }
    }
}

// ============================================================================
// Kernel 2: forward recurrence. One WG (512 thr) per batch element.
//
// v2 structure: 4-way k-split to halve LDS data-return traffic (which the
// v1 counters showed to be the bound: 393 KB/step @ ~85 B/cyc == measured
// 4632 cyc/step).
//   lane l: m = l&15 selects j pair, g = (l>>4)&3 selects k-range [g*64,g*64+64)
//   Each thread computes PARTIAL dots (its 64 ks) for 8 rows:
//     {i,f,g,o} x {ja, ja+16},  ja = wv*32 + m
//   Weights: 48 ks/row resident in VGPRs (8*24 half2 = 192 VGPRs, same
//   proven residency as v1); last 16 ks/row in 128 KB LDS.
//   h read per thread: only its 64-half slice (128 B vs v1's 512 B).
//   Partials combined via permlane16/32 self-swap all-reduce (VALU pipe):
//     xor16 (partner has complementary k-half, same rows) -> pick own-j gates
//     xor32 (partner has remaining k-half, same j)        -> full preacts
//   All 4 gates end up in every lane -> c,h computed locally (lanes l and
//   l^32 redundantly share a j). h stored in 4 stagger-offset LDS copies
//   (528 B stride) so the four 16-lane-broadcast b128 h-reads hit disjoint
//   bank groups. One barrier per step (ping-pong h buffers), as in v1.
// ============================================================================
__global__ __attribute__((amdgpu_flat_work_group_size(512, 512), amdgpu_waves_per_eu(2, 2)))
void lstm_fwd(
    const float* __restrict__ Whh, const _Float16* __restrict__ XP,
    float* __restrict__ HF)
{
    __shared__ _Float16 wlds[16 * 512 * 8];             // 128 KB: [slot=r*2+cc][thread][8]
    __shared__ __align__(16) _Float16 hbuf[2][1056];    // 2 x (4 copies x 264 halves)

    const int t = threadIdx.x;
    const int b = blockIdx.x;
    const int l = t & 63;
    const int wv = t >> 6;
    const int m = l & 15;
    const int g = (l >> 4) & 3;          // k-quadrant
    const bool rowev = ((l >> 4) & 1) == 0;
    const int j = wv * 32 + (l & 31);    // this lane's output gate index
    const int ja = wv * 32 + m;
    const int kbase = g * 64;

    int rows[8];
    rows[0] = ja;       rows[1] = ja + 256; rows[2] = ja + 512; rows[3] = ja + 768;
    rows[4] = ja + 16;  rows[5] = ja + 272; rows[6] = ja + 528; rows[7] = ja + 784;

    // ---- resident weights: ks [kbase, kbase+48) for all 8 rows (192 VGPRs) ----
    half2v w[8][24];
#pragma unroll
    for (int r = 0; r < 8; ++r) {
        const float* wr = Whh + (size_t)rows[r] * HH + kbase;
#pragma unroll
        for (int i4 = 0; i4 < 12; ++i4) {
            float4 v = *(const float4*)(wr + i4 * 4);
            w[r][i4 * 2]     = half2v{(_Float16)v.x, (_Float16)v.y};
            w[r][i4 * 2 + 1] = half2v{(_Float16)v.z, (_Float16)v.w};
        }
        // ---- LDS weights: ks [kbase+48, kbase+64), per-thread-owned slots ----
#pragma unroll
        for (int cc = 0; cc < 2; ++cc) {
            float4 a  = *(const float4*)(wr + 48 + cc * 8);
            float4 b4 = *(const float4*)(wr + 48 + cc * 8 + 4);
            half8v hv = {(_Float16)a.x,  (_Float16)a.y,  (_Float16)a.z,  (_Float16)a.w,
                         (_Float16)b4.x, (_Float16)b4.y, (_Float16)b4.z, (_Float16)b4.w};
            *(half8v*)(&wlds[(r * 2 + cc) * 4096 + t * 8]) = hv;
        }
    }
    if (t < 256) {
        hbuf[0][t]       = (_Float16)0.f;
        hbuf[0][264 + t] = (_Float16)0.f;
        hbuf[0][528 + t] = (_Float16)0.f;
        hbuf[0][792 + t] = (_Float16)0.f;
    }
    float c = 0.0f;
    __syncthreads();

    const _Float16* xp_b = XP + (size_t)b * TT * GG + j;
    _Float16 x0 = xp_b[0], x1 = xp_b[256], x2 = xp_b[512], x3 = xp_b[768];

    const int hoff = g * 328;   // copy-g base (g*264) + k-offset (g*64), in halves

    for (int ts = 0; ts < TT; ++ts) {
        const int p = ts & 1;
        const _Float16* hrd = &hbuf[p][hoff];
        // prefetch next step's xp (full step of latency to land)
        const _Float16* xp_n = xp_b + ((ts < TT - 1) ? GG : 0);
        const _Float16 nx0 = xp_n[0], nx1 = xp_n[256], nx2 = xp_n[512], nx3 = xp_n[768];

        float s[8] = {0.f, 0.f, 0.f, 0.f, 0.f, 0.f, 0.f, 0.f};
#pragma unroll
        for (int ch = 0; ch < 6; ++ch) {   // VGPR-weight chunks (ks kbase..kbase+48)
            half8v hv = *(const half8v*)(hrd + ch * 8);
            half2v h0 = __builtin_shufflevector(hv, hv, 0, 1);
            half2v h1 = __builtin_shufflevector(hv, hv, 2, 3);
            half2v h2 = __builtin_shufflevector(hv, hv, 4, 5);
            half2v h3 = __builtin_shufflevector(hv, hv, 6, 7);
#pragma unroll
            for (int r = 0; r < 8; ++r) {
                s[r] = FDOT2(h0, w[r][ch * 4 + 0], s[r]);
                s[r] = FDOT2(h1, w[r][ch * 4 + 1], s[r]);
                s[r] = FDOT2(h2, w[r][ch * 4 + 2], s[r]);
                s[r] = FDOT2(h3, w[r][ch * 4 + 3], s[r]);
            }
        }
#pragma unroll
        for (int cc = 0; cc < 2; ++cc) {   // LDS-weight chunks (ks kbase+48..kbase+64)
            half8v hv = *(const half8v*)(hrd + (6 + cc) * 8);
            half2v h0 = __builtin_shufflevector(hv, hv, 0, 1);
            half2v h1 = __builtin_shufflevector(hv, hv, 2, 3);
            half2v h2 = __builtin_shufflevector(hv, hv, 4, 5);
            half2v h3 = __builtin_shufflevector(hv, hv, 6, 7);
#pragma unroll
            for (int r = 0; r < 8; ++r) {
                half8v wl = *(const half8v*)(&wlds[(r * 2 + cc) * 4096 + t * 8]);
                half2v q0 = __builtin_shufflevector(wl, wl, 0, 1);
                half2v q1 = __builtin_shufflevector(wl, wl, 2, 3);
                half2v q2 = __builtin_shufflevector(wl, wl, 4, 5);
                half2v q3 = __builtin_shufflevector(wl, wl, 6, 7);
                s[r] = FDOT2(h0, q0, s[r]);
                s[r] = FDOT2(h1, q1, s[r]);
                s[r] = FDOT2(h2, q2, s[r]);
                s[r] = FDOT2(h3, q3, s[r]);
            }
        }

        // xor16 all-reduce each slot (partner: same rows, complementary k-half)
        const float t0 = xred16(s[0]), t1 = xred16(s[1]), t2 = xred16(s[2]), t3 = xred16(s[3]);
        const float t4 = xred16(s[4]), t5 = xred16(s[5]), t6 = xred16(s[6]), t7 = xred16(s[7]);
        // keep this lane's j-gates
        float vi = rowev ? t0 : t4;
        float vf = rowev ? t1 : t5;
        float vg = rowev ? t2 : t6;
        float vo = rowev ? t3 : t7;
        // xor32 all-reduce finishes k (partner: same j, remaining k-half)
        vi = xred32(vi); vf = xred32(vf); vg = xred32(vg); vo = xred32(vo);

        const float gi = vi + (float)x0;
        const float gf = vf + (float)x1;
        const float gG = vg + (float)x2;
        const float go = vo + (float)x3;
        c = sigm(gf) * c + sigm(gi) * tanh_(gG);
        const float h = sigm(go) * tanh_(c);

        // write h into the 4 staggered copies of the other buffer:
        // lanes l<32 fill copies {0,1}, lanes l>=32 fill copies {2,3}
        _Float16* hw = &hbuf[p ^ 1][0];
        const int cp = (l < 32) ? 0 : 528;
        const _Float16 hh = (_Float16)h;
        hw[cp + j] = hh;
        hw[cp + 264 + j] = hh;
        if (ts == TT - 1 && l < 32) HF[(size_t)b * HH + j] = h;
        __syncthreads();

        x0 = nx0; x1 = nx1; x2 = nx2; x3 = nx3;
        xp_b = xp_n;
    }
}

// ============================================================================
// Kernel 3: backward direction = ONE cell step on x[:, T-1] with h0=c0=0.
// ============================================================================
__global__ __launch_bounds__(256) void lstm_bwd(
    const float* __restrict__ X, const float* __restrict__ Wih,
    const float* __restrict__ bb, float* __restrict__ HB)
{
    __shared__ float xs[II];
    const int b = blockIdx.x, t = threadIdx.x;
    const float* xrow = X + ((size_t)b * TT + (TT - 1)) * II;
    if (t < 75) *(float4*)(&xs[t * 4]) = *(const float4*)(xrow + t * 4);
    __syncthreads();
    if (t < HH) {
        float ai = 0.f, ag = 0.f, ao = 0.f;
        const float4* wi = (const float4*)(Wih + (size_t)t * II);
        const float4* wg = (const float4*)(Wih + (size_t)(t + 512) * II);
        const float4* wo = (const float4*)(Wih + (size_t)(t + 768) * II);
        for (int k4 = 0; k4 < 75; ++k4) {
            float4 xv = *(const float4*)(&xs[k4 * 4]);
            float4 a = wi[k4], g4 = wg[k4], o4 = wo[k4];
            ai += xv.x * a.x + xv.y * a.y + xv.z * a.z + xv.w * a.w;
            ag += xv.x * g4.x + xv.y * g4.y + xv.z * g4.z + xv.w * g4.w;
            ao += xv.x * o4.x + xv.y * o4.y + xv.z * o4.z + xv.w * o4.w;
        }
        ai += bb[t];
        ag += bb[t + 512];
        ao += bb[t + 768];
        const float cg = sigm(ai) * tanh_(ag);
        HB[(size_t)b * HH + t] = sigm(ao) * tanh_(cg);
    }
}

// ============================================================================
// Kernel 4: out[b][jj] = [hf|hb] . W_lin[jj] + b_lin[jj]
// ============================================================================
__global__ __launch_bounds__(256) void final_k(
    const float* __restrict__ HF, const float* __restrict__ HB,
    const float* __restrict__ Wlin, const float* __restrict__ blin,
    float* __restrict__ OUT)
{
    const int t = threadIdx.x;
    const int b = t >> 1, jj = t & 1;
    float acc = blin[jj];
    const float* wf = Wlin + jj * 512;
    const float* wb = Wlin + jj * 512 + 256;
    const float* hf = HF + (size_t)b * HH;
    const float* hb = HB + (size_t)b * HH;
    for (int k = 0; k < HH; k += 4) {
        float4 h4 = *(const float4*)(hf + k);
        float4 w4 = *(const float4*)(wf + k);
        float4 g4 = *(const float4*)(hb + k);
        float4 v4 = *(const float4*)(wb + k);
        acc += h4.x * w4.x + h4.y * w4.y + h4.z * w4.z + h4.w * w4.w;
        acc += g4.x * v4.x + g4.y * v4.y + g4.z * v4.z + g4.w * v4.w;
    }
    OUT[b * 2 + jj] = acc;
}

// ============================================================================
extern "C" void kernel_launch(void* const* d_in, const int* in_sizes, int n_in,
                              void* d_out, int out_size, void* d_ws, size_t ws_size,
                              hipStream_t stream)
{
    const float* x = (const float*)d_in[0];
    const float* Wihf = (const float*)d_in[1];
    const float* Whhf = (const float*)d_in[2];
    const float* bf = (const float*)d_in[3];
    const float* Wihb = (const float*)d_in[4];
    const float* Whhb = (const float*)d_in[5];
    const float* bbv = (const float*)d_in[6];
    const float* Wlin = (const float*)d_in[7];
    const float* blin = (const float*)d_in[8];
    float* out = (float*)d_out;
    (void)Whhb; (void)in_sizes; (void)n_in; (void)out_size; (void)ws_size;

    // workspace: xp fp16 (134,217,728 B) | hf f32 | hb f32
    _Float16* xp = (_Float16*)d_ws;
    float* hf = (float*)((char*)d_ws + (size_t)BB * TT * GG * 2);
    float* hb = hf + (size_t)BB * HH;

    lstm_bwd<<<BB, 256, 0, stream>>>(x, Wihb, bbv, hb);
    gemm_xp<<<dim3(GG / 128, (BB * TT) / 128), 256, 0, stream>>>(x, Wihf, bf, xp);
    lstm_fwd<<<BB, 512, 0, stream>>>(Whhf, xp, hf);
    final_k<<<1, 256, 0, stream>>>(hf, hb, Wlin, blin, out);
}

// Round 2
// 1241.444 us; speedup vs baseline: 1.1684x; 1.1684x over previous
//
#include <hip/hip_runtime.h>
#include <cstdint>
#include <cstddef>

// ---------- types ----------
typedef _Float16 half2v __attribute__((ext_vector_type(2)));
typedef _Float16 half4v __attribute__((ext_vector_type(4)));
typedef _Float16 half8v __attribute__((ext_vector_type(8)));
typedef float f32x4 __attribute__((ext_vector_type(4)));

#if __has_builtin(__builtin_amdgcn_fdot2)
#define FDOT2(a, b, c) __builtin_amdgcn_fdot2((a), (b), (c), false)
#else
static __device__ __forceinline__ float fdot2_fb(half2v a, half2v b, float c) {
    return c + (float)a[0] * (float)b[0] + (float)a[1] * (float)b[1];
}
#define FDOT2(a, b, c) fdot2_fb((a), (b), (c))
#endif

__device__ __forceinline__ float sigm(float x) { return 1.0f / (1.0f + __expf(-x)); }
__device__ __forceinline__ float tanh_(float x) { return 1.0f - 2.0f / (__expf(2.0f * x) + 1.0f); }

// Problem constants
#define BB 128
#define TT 512
#define II 300
#define IIP 320   // padded K for fp16 path
#define HH 256
#define GG 1024  // 4*H

// ============================================================================
// Kernel 0: convert X (65536x300 f32) and W_ih_f (1024x300 f32) to fp16 with
// zero-padded K=320 rows, enabling 16B-aligned global_load_lds in the GEMM.
// ============================================================================
__global__ __launch_bounds__(256) void cvt_xw(
    const float* __restrict__ X, const float* __restrict__ W,
    _Float16* __restrict__ Xh, _Float16* __restrict__ Wh)
{
    const int total = (65536 + 1024) * 40;   // 8-elem chunks per padded row
    for (int c = blockIdx.x * 256 + threadIdx.x; c < total; c += gridDim.x * 256) {
        const int row = c / 40;
        const int ch = c - row * 40;
        const int k0 = ch * 8;
        const float* src;
        _Float16* dst;
        if (row < 65536) {
            src = X + (size_t)row * II;
            dst = Xh + (size_t)row * IIP;
        } else {
            src = W + (size_t)(row - 65536) * II;
            dst = Wh + (size_t)(row - 65536) * IIP;
        }
        half8v hv;
        if (k0 + 8 <= II) {
            float4 a = *(const float4*)(src + k0);
            float4 b = *(const float4*)(src + k0 + 4);
            hv = half8v{(_Float16)a.x, (_Float16)a.y, (_Float16)a.z, (_Float16)a.w,
                        (_Float16)b.x, (_Float16)b.y, (_Float16)b.z, (_Float16)b.w};
        } else {
#pragma unroll
            for (int q = 0; q < 8; ++q) {
                const int k = k0 + q;
                hv[q] = (k < II) ? (_Float16)src[k] : (_Float16)0.f;
            }
        }
        *(half8v*)(dst + k0) = hv;
    }
}

// ============================================================================
// Kernel 1b: xp GEMM, fp16 inputs via global_load_lds (m97 structure).
// XP[m][n] = sum_k Xh[m][k]*Wh[n][k] + bias[n].  M=65536, N=1024, K=320.
// 128x128 tile / 256 thr / BK=32 / 10 K-steps.
// LDS layout [m4][k4][m16][8] (identical to the proven f32-staged kernel);
// global_load_lds writes lane-linear, so the per-lane GLOBAL source is
// pre-swizzled to match (m173 pattern): chunk c -> row=(c>>6)*16+(c&15),
// kchunk=(c>>4)&3.
// ============================================================================
#if __has_builtin(__builtin_amdgcn_global_load_lds)
#define HAVE_GLL 1
__device__ __forceinline__ void gll16(const _Float16* g, _Float16* l) {
    __builtin_amdgcn_global_load_lds(
        (const __attribute__((address_space(1))) void*)g,
        (__attribute__((address_space(3))) void*)l, 16, 0, 0);
}
#else
#define HAVE_GLL 0
#endif

__global__ __launch_bounds__(256) void gemm_xp_h(
    const _Float16* __restrict__ Xh, const _Float16* __restrict__ Wh,
    const float* __restrict__ bias, _Float16* __restrict__ XP)
{
    __shared__ __align__(16) _Float16 As[128 * 32];
    __shared__ __align__(16) _Float16 Bs[128 * 32];

    const int t = threadIdx.x;
    const int m0 = blockIdx.y * 128;
    const int n0 = blockIdx.x * 128;
    const int lane = t & 63;
    const int wv = t >> 6;
    const int mq = (wv >> 1) * 4;
    const int nq = (wv & 1) * 4;

    // staging chunk decode (two rounds per tile; c is lane-linear per round)
    int rowd[2], k4d[2], cidx[2];
#pragma unroll
    for (int r = 0; r < 2; ++r) {
        const int c = wv * 128 + r * 64 + lane;
        cidx[r] = c;
        rowd[r] = ((c >> 6) << 4) | (c & 15);
        k4d[r] = (c >> 4) & 3;
    }

    f32x4 acc[4][4];
#pragma unroll
    for (int i = 0; i < 4; ++i)
#pragma unroll
        for (int j = 0; j < 4; ++j) acc[i][j] = f32x4{0.f, 0.f, 0.f, 0.f};

    for (int kc = 0; kc < IIP; kc += 32) {
        __syncthreads();
#pragma unroll
        for (int r = 0; r < 2; ++r) {
            const _Float16* ga = Xh + (size_t)(m0 + rowd[r]) * IIP + kc + k4d[r] * 8;
            const _Float16* gb = Wh + (size_t)(n0 + rowd[r]) * IIP + kc + k4d[r] * 8;
#if HAVE_GLL
            gll16(ga, &As[cidx[r] * 8]);
            gll16(gb, &Bs[cidx[r] * 8]);
#else
            *(half8v*)(&As[cidx[r] * 8]) = *(const half8v*)ga;
            *(half8v*)(&Bs[cidx[r] * 8]) = *(const half8v*)gb;
#endif
        }
        __syncthreads();

        half8v af[4], bf[4];
#pragma unroll
        for (int i = 0; i < 4; ++i) {
            af[i] = *(const half8v*)(&As[(mq + i) * 512 + (lane >> 4) * 128 + (lane & 15) * 8]);
            bf[i] = *(const half8v*)(&Bs[(nq + i) * 512 + (lane >> 4) * 128 + (lane & 15) * 8]);
        }
#pragma unroll
        for (int i = 0; i < 4; ++i)
#pragma unroll
            for (int j = 0; j < 4; ++j)
                acc[i][j] = __builtin_amdgcn_mfma_f32_16x16x32_f16(af[i], bf[j], acc[i][j], 0, 0, 0);
    }

#pragma unroll
    for (int j = 0; j < 4; ++j) {
        const int n = n0 + (nq + j) * 16 + (lane & 15);
        const float bv = bias[n];
#pragma unroll
        for (int i = 0; i < 4; ++i) {
#pragma unroll
            for (int r = 0; r < 4; ++r) {
                const int m = m0 + (mq + i) * 16 + (lane >> 4) * 4 + r;
                XP[(size_t)m * GG + n] = (_Float16)(acc[i][j][r] + bv);
            }
        }
    }
}

// ============================================================================
// Kernel 1 (fallback): xp GEMM from f32 inputs (the proven v1 kernel).
// ============================================================================
__global__ __launch_bounds__(256, 3) void gemm_xp(
    const float* __restrict__ X, const float* __restrict__ W,
    const float* __restrict__ bias, _Float16* __restrict__ XP)
{
    __shared__ _Float16 As[128 * 32];
    __shared__ _Float16 Bs[128 * 32];

    const int t = threadIdx.x;
    const int m0 = blockIdx.y * 128;
    const int n0 = blockIdx.x * 128;
    const int kpos = t & 7;
    const int rbase = t >> 3;
    const int lane = t & 63;
    const int wv = t >> 6;
    const int mq = (wv >> 1) * 4;
    const int nq = (wv & 1) * 4;

    f32x4 acc[4][4];
#pragma unroll
    for (int i = 0; i < 4; ++i)
#pragma unroll
        for (int j = 0; j < 4; ++j) acc[i][j] = f32x4{0.f, 0.f, 0.f, 0.f};

    for (int kc = 0; kc < 320; kc += 32) {
        __syncthreads();
        const int k0 = kc + kpos * 4;
#pragma unroll
        for (int rr = 0; rr < 4; ++rr) {
            const int row = rbase + rr * 32;
            float4 va = {0.f, 0.f, 0.f, 0.f}, vb = {0.f, 0.f, 0.f, 0.f};
            if (k0 < 300) {
                va = *(const float4*)(X + (size_t)(m0 + row) * II + k0);
                vb = *(const float4*)(W + (size_t)(n0 + row) * II + k0);
            }
            const int idx = (row >> 4) * 512 + (kpos >> 1) * 128 + (row & 15) * 8 + (kpos & 1) * 4;
            half4v ha = {(_Float16)va.x, (_Float16)va.y, (_Float16)va.z, (_Float16)va.w};
            half4v hb = {(_Float16)vb.x, (_Float16)vb.y, (_Float16)vb.z, (_Float16)vb.w};
            *(half4v*)(&As[idx]) = ha;
            *(half4v*)(&Bs[idx]) = hb;
        }
        __syncthreads();

        half8v af[4], bf[4];
#pragma unroll
        for (int i = 0; i < 4; ++i) {
            af[i] = *(const half8v*)(&As[(mq + i) * 512 + (lane >> 4) * 128 + (lane & 15) * 8]);
            bf[i] = *(const half8v*)(&Bs[(nq + i) * 512 + (lane >> 4) * 128 + (lane & 15) * 8]);
        }
#pragma unroll
        for (int i = 0; i < 4; ++i)
#pragma unroll
            for (int j = 0; j < 4; ++j)
                acc[i][j] = __builtin_amdgcn_mfma_f32_16x16x32_f16(af[i], bf[j], acc[i][j], 0, 0, 0);
    }

#pragma unroll
    for (int j = 0; j < 4; ++j) {
        const int n = n0 + (nq + j) * 16 + (lane & 15);
        const float bv = bias[n];
#pragma unroll
        for (int i = 0; i < 4; ++i) {
#pragma unroll
            for (int r = 0; r < 4; ++r) {
                const int m = m0 + (mq + i) * 16 + (lane >> 4) * 4 + r;
                XP[(size_t)m * GG + n] = (_Float16)(acc[i][j][r] + bv);
            }
        }
    }
}

// ============================================================================
// Kernel 2: forward recurrence (v1 verbatim — proven 988 µs).
// One WG (512 thr) per batch element.
// Row mapping (partner-in-wave): wave wv, lane l; j = wv*32 + (l&31).
//   l<32  -> rows (i_j, g_j) = (j,     j+512)
//   l>=32 -> rows (f_j, o_j) = (j+256, j+768)
// Preact exchange via __shfl_xor(.,32) (same wave, no barrier); c,h computed
// redundantly by the pair. h ping-pongs between 2 LDS buffers -> ONE barrier
// per step. Weights: k in [0,192) resident (192 VGPRs of half2, forced by
// amdgpu_waves_per_eu(2,2) -> 256-reg budget); k in [192,256) in 128 KB LDS.
// ============================================================================
__global__ __attribute__((amdgpu_flat_work_group_size(512, 512), amdgpu_waves_per_eu(2, 2)))
void lstm_fwd(
    const float* __restrict__ Whh, const _Float16* __restrict__ XP,
    float* __restrict__ HF)
{
    __shared__ _Float16 wlds[8 * GG * 8];            // 128 KB: [grp][row][8]
    __shared__ __align__(16) _Float16 hlds[2][HH];   // 1 KB ping-pong

    const int t = threadIdx.x;
    const int b = blockIdx.x;
    const int l = t & 63;
    const int wv = t >> 6;
    const int half = l >> 5;               // 0: (i,g) rows, 1: (f,o) rows
    const int j = wv * 32 + (l & 31);      // gate index 0..255
    const int row0 = j + (half ? 256 : 0); // i_j or f_j
    const int row1 = row0 + 512;           // g_j or o_j

    // ---- resident weights: k = 0..191 for both owned rows (192 VGPRs) ----
    half2v w0[96], w1[96];
#pragma unroll
    for (int i = 0; i < 48; ++i) {
        float4 v = *(const float4*)(Whh + (size_t)row0 * HH + i * 4);
        w0[2 * i]     = half2v{(_Float16)v.x, (_Float16)v.y};
        w0[2 * i + 1] = half2v{(_Float16)v.z, (_Float16)v.w};
    }
#pragma unroll
    for (int i = 0; i < 48; ++i) {
        float4 v = *(const float4*)(Whh + (size_t)row1 * HH + i * 4);
        w1[2 * i]     = half2v{(_Float16)v.x, (_Float16)v.y};
        w1[2 * i + 1] = half2v{(_Float16)v.z, (_Float16)v.w};
    }
    // ---- LDS weights: k = 192..255, filled by row index t and t+512 ----
#pragma unroll
    for (int grp = 0; grp < 8; ++grp) {
        float4 a  = *(const float4*)(Whh + (size_t)t * HH + 192 + grp * 8);
        float4 c4 = *(const float4*)(Whh + (size_t)t * HH + 192 + grp * 8 + 4);
        half8v hv = {(_Float16)a.x, (_Float16)a.y, (_Float16)a.z, (_Float16)a.w,
                     (_Float16)c4.x, (_Float16)c4.y, (_Float16)c4.z, (_Float16)c4.w};
        *(half8v*)(&wlds[grp * (GG * 8) + t * 8]) = hv;
        float4 a2 = *(const float4*)(Whh + (size_t)(t + 512) * HH + 192 + grp * 8);
        float4 c2 = *(const float4*)(Whh + (size_t)(t + 512) * HH + 192 + grp * 8 + 4);
        half8v hv2 = {(_Float16)a2.x, (_Float16)a2.y, (_Float16)a2.z, (_Float16)a2.w,
                      (_Float16)c2.x, (_Float16)c2.y, (_Float16)c2.z, (_Float16)c2.w};
        *(half8v*)(&wlds[grp * (GG * 8) + (t + 512) * 8]) = hv2;
    }
    if (t < HH) hlds[0][t] = (_Float16)0.f;
    float c = 0.0f;
    __syncthreads();

    const _Float16* xp_b = XP + (size_t)b * TT * GG;
    _Float16 x0 = xp_b[row0];
    _Float16 x1 = xp_b[row1];

    for (int ts = 0; ts < TT; ++ts) {
        const int p = ts & 1;
        const _Float16* hrd = &hlds[p][0];
        // prefetch next step's xp (full step of latency to land)
        const _Float16* xp_n = xp_b + ((ts < TT - 1) ? GG : 0);
        const _Float16 nx0 = xp_n[row0];
        const _Float16 nx1 = xp_n[row1];

        float a0 = 0.f, a1 = 0.f;
#pragma unroll
        for (int cq = 0; cq < 24; ++cq) {  // k = 0..191 from VGPR weights
            half8v hv = *(const half8v*)(&hrd[cq * 8]);
            half2v h0 = __builtin_shufflevector(hv, hv, 0, 1);
            half2v h1 = __builtin_shufflevector(hv, hv, 2, 3);
            half2v h2 = __builtin_shufflevector(hv, hv, 4, 5);
            half2v h3 = __builtin_shufflevector(hv, hv, 6, 7);
            a0 = FDOT2(h0, w0[cq * 4 + 0], a0);
            a1 = FDOT2(h0, w1[cq * 4 + 0], a1);
            a0 = FDOT2(h1, w0[cq * 4 + 1], a0);
            a1 = FDOT2(h1, w1[cq * 4 + 1], a1);
            a0 = FDOT2(h2, w0[cq * 4 + 2], a0);
            a1 = FDOT2(h2, w1[cq * 4 + 2], a1);
            a0 = FDOT2(h3, w0[cq * 4 + 3], a0);
            a1 = FDOT2(h3, w1[cq * 4 + 3], a1);
        }
#define LDS_W_STEP(I0, I1)                                                 \
        {                                                                  \
            half2v hp  = __builtin_shufflevector(hv, hv, I0, I1);          \
            half2v wap = __builtin_shufflevector(wa, wa, I0, I1);          \
            half2v wbp = __builtin_shufflevector(wb, wb, I0, I1);          \
            a0 = FDOT2(hp, wap, a0);                                       \
            a1 = FDOT2(hp, wbp, a1);                                       \
        }
#pragma unroll
        for (int grp = 0; grp < 8; ++grp) {  // k = 192..255 from LDS weights
            half8v hv = *(const half8v*)(&hrd[192 + grp * 8]);
            half8v wa = *(const half8v*)(&wlds[grp * (GG * 8) + row0 * 8]);
            half8v wb = *(const half8v*)(&wlds[grp * (GG * 8) + row1 * 8]);
            LDS_W_STEP(0, 1)
            LDS_W_STEP(2, 3)
            LDS_W_STEP(4, 5)
            LDS_W_STEP(6, 7)
        }
#undef LDS_W_STEP
        const float o0 = a0 + (float)x0;
        const float o1 = a1 + (float)x1;
        // partner exchange within the wave (lanes l <-> l^32)
        const float p0 = __shfl_xor(o0, 32, 64);
        const float p1 = __shfl_xor(o1, 32, 64);
        const float gi = half ? p0 : o0;
        const float gg = half ? p1 : o1;
        const float gf = half ? o0 : p0;
        const float go = half ? o1 : p1;
        c = sigm(gf) * c + sigm(gi) * tanh_(gg);
        const float h = sigm(go) * tanh_(c);
        if (!half) {
            hlds[p ^ 1][j] = (_Float16)h;
            if (ts == TT - 1) HF[(size_t)b * HH + j] = h;
        }
        __syncthreads();

        x0 = nx0;
        x1 = nx1;
        xp_b = xp_n;
    }
}

// ============================================================================
// Kernel 3: backward direction = ONE cell step on x[:, T-1] with h0=c0=0.
// ============================================================================
__global__ __launch_bounds__(256) void lstm_bwd(
    const float* __restrict__ X, const float* __restrict__ Wih,
    const float* __restrict__ bb, float* __restrict__ HB)
{
    __shared__ float xs[II];
    const int b = blockIdx.x, t = threadIdx.x;
    const float* xrow = X + ((size_t)b * TT + (TT - 1)) * II;
    if (t < 75) *(float4*)(&xs[t * 4]) = *(const float4*)(xrow + t * 4);
    __syncthreads();
    if (t < HH) {
        float ai = 0.f, ag = 0.f, ao = 0.f;
        const float4* wi = (const float4*)(Wih + (size_t)t * II);
        const float4* wg = (const float4*)(Wih + (size_t)(t + 512) * II);
        const float4* wo = (const float4*)(Wih + (size_t)(t + 768) * II);
        for (int k4 = 0; k4 < 75; ++k4) {
            float4 xv = *(const float4*)(&xs[k4 * 4]);
            float4 a = wi[k4], g4 = wg[k4], o4 = wo[k4];
            ai += xv.x * a.x + xv.y * a.y + xv.z * a.z + xv.w * a.w;
            ag += xv.x * g4.x + xv.y * g4.y + xv.z * g4.z + xv.w * g4.w;
            ao += xv.x * o4.x + xv.y * o4.y + xv.z * o4.z + xv.w * o4.w;
        }
        ai += bb[t];
        ag += bb[t + 512];
        ao += bb[t + 768];
        const float cg = sigm(ai) * tanh_(ag);
        HB[(size_t)b * HH + t] = sigm(ao) * tanh_(cg);
    }
}

// ============================================================================
// Kernel 4: out[b][jj] = [hf|hb] . W_lin[jj] + b_lin[jj]
// ============================================================================
__global__ __launch_bounds__(256) void final_k(
    const float* __restrict__ HF, const float* __restrict__ HB,
    const float* __restrict__ Wlin, const float* __restrict__ blin,
    float* __restrict__ OUT)
{
    const int t = threadIdx.x;
    const int b = t >> 1, jj = t & 1;
    float acc = blin[jj];
    const float* wf = Wlin + jj * 512;
    const float* wb = Wlin + jj * 512 + 256;
    const float* hf = HF + (size_t)b * HH;
    const float* hb = HB + (size_t)b * HH;
    for (int k = 0; k < HH; k += 4) {
        float4 h4 = *(const float4*)(hf + k);
        float4 w4 = *(const float4*)(wf + k);
        float4 g4 = *(const float4*)(hb + k);
        float4 v4 = *(const float4*)(wb + k);
        acc += h4.x * w4.x + h4.y * w4.y + h4.z * w4.z + h4.w * w4.w;
        acc += g4.x * v4.x + g4.y * v4.y + g4.z * v4.z + g4.w * v4.w;
    }
    OUT[b * 2 + jj] = acc;
}

// ============================================================================
extern "C" void kernel_launch(void* const* d_in, const int* in_sizes, int n_in,
                              void* d_out, int out_size, void* d_ws, size_t ws_size,
                              hipStream_t stream)
{
    const float* x = (const float*)d_in[0];
    const float* Wihf = (const float*)d_in[1];
    const float* Whhf = (const float*)d_in[2];
    const float* bf = (const float*)d_in[3];
    const float* Wihb = (const float*)d_in[4];
    const float* Whhb = (const float*)d_in[5];
    const float* bbv = (const float*)d_in[6];
    const float* Wlin = (const float*)d_in[7];
    const float* blin = (const float*)d_in[8];
    float* out = (float*)d_out;
    (void)Whhb; (void)in_sizes; (void)n_in; (void)out_size;

    // workspace layout: xp fp16 | hf f32 | hb f32 | Xh fp16 | Wh fp16
    const size_t XP_B = (size_t)BB * TT * GG * 2;            // 134,217,728
    const size_t H_B  = (size_t)BB * HH * 4;                 // 131,072
    const size_t XH_B = (size_t)65536 * IIP * 2;             // 41,943,040
    const size_t WH_B = (size_t)GG * IIP * 2;                // 655,360

    _Float16* xp = (_Float16*)d_ws;
    float* hf = (float*)((char*)d_ws + XP_B);
    float* hb = hf + (size_t)BB * HH;
    _Float16* Xh = (_Float16*)((char*)d_ws + XP_B + 2 * H_B);
    _Float16* Wh = Xh + (size_t)65536 * IIP;

    lstm_bwd<<<BB, 256, 0, stream>>>(x, Wihb, bbv, hb);
    if (ws_size >= XP_B + 2 * H_B + XH_B + WH_B) {
        cvt_xw<<<2048, 256, 0, stream>>>(x, Wihf, Xh, Wh);
        gemm_xp_h<<<dim3(GG / 128, (BB * TT) / 128), 256, 0, stream>>>(Xh, Wh, bf, xp);
    } else {
        gemm_xp<<<dim3(GG / 128, (BB * TT) / 128), 256, 0, stream>>>(x, Wihf, bf, xp);
    }
    lstm_fwd<<<BB, 512, 0, stream>>>(Whhf, xp, hf);
    final_k<<<1, 256, 0, stream>>>(hf, hb, Wlin, blin, out);
}